// Round 19
// baseline (236.323 us; speedup 1.0000x reference)
//
#include <hip/hip_runtime.h>

constexpr int kNR = 40000;
constexpr int kNU = 30000;
constexpr int kNP = 30000;
constexpr int kN  = 100000;          // total nodes
constexpr int kE  = 1600000;         // edges
constexpr int kF  = 128;             // feature/hidden dim
constexpr int kC  = 40;              // classes
constexpr int kBN = 64;              // nodes per bucket
constexpr int kNB = (kN + kBN - 1) / kBN;   // 1563 buckets
constexpr int kNBp = 1600;           // padded bucket-count stride
constexpr int kCH = 256;             // edge chunks (count/scan granularity)
constexpr int kCE = kE / kCH;        // 6250 edges per chunk
constexpr int kSG = 1;               // chunks per scatter block (256 blocks)
constexpr int kStash = 2048;         // LDS pair-stash capacity (avg bucket 1024)
constexpr int kPackB = 196;          // pack blocks (512 thr): 196*512 >= kN
constexpr int kSetupB = kPackB + 2 + kCH;   // 454 blocks total

typedef __attribute__((ext_vector_type(8))) short bf16x8;   // MFMA A/B frag
typedef __attribute__((ext_vector_type(4))) float f32x4;    // MFMA C/D frag

// ---------- bf16 helpers ----------
__device__ __forceinline__ float bf_to_f(unsigned short h) {
    union { unsigned int i; float f; } u; u.i = ((unsigned int)h) << 16; return u.f;
}
__device__ __forceinline__ unsigned short f_to_bf(float f) {
    union { unsigned int i; float f; } u; u.f = f;
    unsigned int r = u.i + 0x7FFFu + ((u.i >> 16) & 1u);   // RNE
    return (unsigned short)(r >> 16);
}
__device__ __forceinline__ float2 bf2_to_f2(unsigned int p) {
    union { unsigned int i; float f; } lo, hi;
    lo.i = (p & 0xFFFFu) << 16;
    hi.i = p & 0xFFFF0000u;
    return make_float2(lo.f, hi.f);
}
__device__ __forceinline__ unsigned int pack_bf2(float a, float b) {
    return (unsigned int)f_to_bf(a) | ((unsigned int)f_to_bf(b) << 16);
}
__device__ __forceinline__ float ldf(const void* p, int i, int isbf) {
    return isbf ? bf_to_f(((const unsigned short*)p)[i]) : ((const float*)p)[i];
}
__device__ __forceinline__ int lde(const int* p, int i, int is64) {
    return is64 ? p[2 * i] : p[i];
}

// ---------- sniff dtypes -> flags[0]=isbf, flags[1]=is64; zero done-counter flags[8] ----------
__global__ void gcn_sniff(const unsigned int* __restrict__ w1w,
                          const int* __restrict__ eiw, int* __restrict__ flags) {
    if (blockIdx.x != 0 || threadIdx.x != 0) return;
    int plaus = 0;
    for (int k = 0; k < 64; k++) {
        unsigned int ax = w1w[k] & 0x7FFFu;
        plaus += (ax == 0u) || (ax > 0x2000u && ax < 0x4000u);
    }
    flags[0] = (plaus >= 48) ? 1 : 0;
    int nz = 0;
    for (int k = 0; k < 64; k++) nz |= eiw[2 * k + 1];
    flags[1] = (nz == 0) ? 1 : 0;
    flags[8] = 0;                       // scanB done-counter (ws is poisoned each launch)
}

// ---------- MERGED setup+count: blocks 0..195 pack | 196 fuse | 197 w2frag | 198..453 count ----------
__global__ void __launch_bounds__(512) gcn_setup(
        const void* __restrict__ xr, const void* __restrict__ xu, const void* __restrict__ xp,
        const void* __restrict__ Wr, const void* __restrict__ br,
        const void* __restrict__ Wu, const void* __restrict__ bu,
        const void* __restrict__ Wp, const void* __restrict__ bp,
        const void* __restrict__ W1, const void* __restrict__ W2,
        const int* __restrict__ ei,
        unsigned short* __restrict__ fwfrag, unsigned short* __restrict__ w2frag,
        uint4* __restrict__ xpack, int* __restrict__ cmat,
        const int* __restrict__ flags) {
    __shared__ __align__(16) char smem[29696];
    int isbf = flags[0];
    int t = threadIdx.x;
    int bx = blockIdx.x;
    if (bx < kPackB) {                       // ---- pack (512 thr) ----
        int n = bx * 512 + t;
        if (n >= kN) return;
        const void* base; int roff, d;
        if (n < kNR)            { base = xr; roff = n * 5;               d = 5; }
        else if (n < kNR + kNU) { base = xu; roff = (n - kNR) * 7;       d = 7; }
        else                    { base = xp; roff = (n - kNR - kNU) * 6; d = 6; }
        float f[8];
        #pragma unroll
        for (int i = 0; i < 8; i++) f[i] = (i < d) ? ldf(base, roff + i, isbf) : 0.f;
        uint4 u;
        u.x = pack_bf2(f[0], f[1]);  u.y = pack_bf2(f[2], f[3]);
        u.z = pack_bf2(f[4], f[5]);  u.w = pack_bf2(f[6], f[7]);
        xpack[n] = u;
    } else if (bx == kPackB) {               // ---- fuse -> fwfrag (split-k, 256 active) ----
        float* sw   = (float*)smem;                          // 10752 B
        float* pacc = (float*)(smem + 10752);                // 10752 B
        unsigned short* flds = (unsigned short*)(smem + 21504);  // 8192 B
        for (int i = t; i < 21 * kF; i += 512) {
            int r = i >> 7, c = i & 127;
            float v;
            if (r < 5)        v = ldf(Wr, r * kF + c, isbf);
            else if (r < 12)  v = ldf(Wu, (r - 5) * kF + c, isbf);
            else if (r < 18)  v = ldf(Wp, (r - 12) * kF + c, isbf);
            else if (r == 18) v = ldf(br, c, isbf);
            else if (r == 19) v = ldf(bu, c, isbf);
            else              v = ldf(bp, c, isbf);
            sw[i] = v;
        }
        __syncthreads();
        {
            bool active = (t < 256);
            int j = t & 127, half = (t >> 7) & 1;
            float acc[21];
            #pragma unroll
            for (int r = 0; r < 21; r++) acc[r] = 0.f;
            if (active) {
                int k0 = half * 64, k1 = k0 + 64;
                for (int k = k0; k < k1; k++) {
                    float w1 = ldf(W1, k * kF + j, isbf);
                    #pragma unroll
                    for (int r = 0; r < 21; r++) acc[r] += sw[r * kF + k] * w1;
                }
            }
            if (active && half == 1) {
                #pragma unroll
                for (int r = 0; r < 21; r++) pacc[r * kF + j] = acc[r];
            }
            __syncthreads();
            if (active && half == 0) {
                #pragma unroll
                for (int r = 0; r < 21; r++) acc[r] += pacc[r * kF + j];
                unsigned short row[32];
                #pragma unroll
                for (int s = 0; s < 32; s++) row[s] = 0;
                #pragma unroll
                for (int i = 0; i < 5; i++) row[0  + i] = f_to_bf(acc[i]);
                #pragma unroll
                for (int i = 0; i < 7; i++) row[8  + i] = f_to_bf(acc[5 + i]);
                #pragma unroll
                for (int i = 0; i < 6; i++) row[16 + i] = f_to_bf(acc[12 + i]);
                row[24] = f_to_bf(acc[18]);  row[25] = f_to_bf(acc[19]);  row[26] = f_to_bf(acc[20]);
                #pragma unroll
                for (int s = 0; s < 32; s++) flds[j * 32 + s] = row[s];
            }
        }
        __syncthreads();
        for (int idx = t; idx < 8 * 64; idx += 512) {
            int t8 = idx >> 6, lane = idx & 63;
            int mm = lane & 15, q = lane >> 4;
            #pragma unroll
            for (int j = 0; j < 8; j++)
                fwfrag[idx * 8 + j] = flds[(16 * t8 + mm) * 32 + q * 8 + j];
        }
    } else if (bx == kPackB + 1) {           // ---- W2 -> w2frag ----
        for (int idx = t; idx < 12 * 64; idx += 512) {
            int st = idx >> 6, lane = idx & 63;
            int s = st / 3, tt = st % 3;
            int mm = lane & 15, q = lane >> 4;
            int cls = 16 * tt + mm;
            #pragma unroll
            for (int j = 0; j < 8; j++) {
                int k = s * 32 + q * 8 + j;
                w2frag[idx * 8 + j] = (cls < kC) ? f_to_bf(ldf(W2, k * kC + cls, isbf))
                                                 : (unsigned short)0;
            }
        }
    } else {                                 // ---- count (chunk = bx - kPackB - 2) ----
        int* cl = (int*)smem;                // 1600 ints
        int is64 = flags[1];
        int blk = bx - kPackB - 2;
        for (int i = t; i < kNBp; i += 512) cl[i] = 0;
        __syncthreads();
        int e0 = blk * kCE, e1 = e0 + kCE;
        for (int eb = e0 + t; eb < e1; eb += 2048) {
            unsigned int d[4]; int ok[4];
            #pragma unroll
            for (int j = 0; j < 4; j++) {
                int e = eb + j * 512;
                ok[j] = (e < e1);
                d[j] = ok[j] ? (unsigned int)lde(ei, kE + e, is64) : 0u;
            }
            #pragma unroll
            for (int j = 0; j < 4; j++)
                if (ok[j] && d[j] < (unsigned int)kN) atomicAdd(&cl[d[j] >> 6], 1);
        }
        __syncthreads();
        for (int i = t; i < kNBp; i += 512) cmat[blk * kNBp + i] = cl[i];
    }
}

// ---------- MERGED scans: per-bucket scan; LAST block also scans bucket totals -> bbase ----------
// Cross-block handoff via device-scope atomics (coherent across XCDs); bbase visibility
// to the next kernel is guaranteed by the dispatch boundary.
__global__ void __launch_bounds__(256) gcn_scanB(const int* __restrict__ cmat,
                                                 int* __restrict__ reloff,
                                                 int* __restrict__ btot,
                                                 int* __restrict__ bbase,
                                                 int* __restrict__ done) {
    __shared__ int lds[256];
    __shared__ int lastFlag;
    int b = blockIdx.x, t = threadIdx.x;
    int v = cmat[t * kNBp + b];
    int incl = v; lds[t] = incl; __syncthreads();
    for (int o = 1; o < 256; o <<= 1) {
        int y = (t >= o) ? lds[t - o] : 0;
        __syncthreads();
        incl += y; lds[t] = incl;
        __syncthreads();
    }
    reloff[b * 256 + t] = incl - v;
    if (t == 255) {
        atomicExch(&btot[b], incl);           // publish (device-scope)
        __threadfence();
        int old = atomicAdd(done, 1);
        lastFlag = (old == kNB - 1) ? 1 : 0;
    }
    __syncthreads();
    if (!lastFlag) return;
    __threadfence();
    // phase 2 (last block only): exclusive scan of 1563 bucket totals
    int v2[7]; int s = 0;
    #pragma unroll
    for (int j = 0; j < 7; j++) {
        int i = t * 7 + j;
        v2[j] = (i < kNB) ? atomicAdd(&btot[i], 0) : 0;   // device-scope read
        s += v2[j];
    }
    __syncthreads();
    int incl2 = s; lds[t] = incl2; __syncthreads();
    for (int o = 1; o < 256; o <<= 1) {
        int y = (t >= o) ? lds[t - o] : 0;
        __syncthreads();
        incl2 += y; lds[t] = incl2;
        __syncthreads();
    }
    int excl = incl2 - s;
    #pragma unroll
    for (int j = 0; j < 7; j++) {
        int i = t * 7 + j;
        if (i < kNB) { bbase[i] = excl; excl += v2[j]; }
    }
    if (t == 255) bbase[kNB] = incl2;
}

// ---------- pass 3: scatter pairs; 256 blocks x 1 chunk (full CU coverage) ----------
__global__ void __launch_bounds__(1024) gcn_scatter(const int* __restrict__ ei,
                                                    const int* __restrict__ bbase,
                                                    const int* __restrict__ reloff,
                                                    unsigned int* __restrict__ pairs,
                                                    const int* __restrict__ flags) {
    __shared__ int cur[kNB];
    int is64 = flags[1];
    int blk = blockIdx.x, t = threadIdx.x;
    int c0 = blk * kSG;
    for (int i = t; i < kNB; i += 1024) cur[i] = bbase[i] + reloff[i * 256 + c0];
    __syncthreads();
    int e0 = c0 * kCE, e1 = e0 + kSG * kCE;
    for (int eb = e0 + t; eb < e1; eb += 4096) {
        unsigned int d[4], s[4]; int ok[4];
        #pragma unroll
        for (int j = 0; j < 4; j++) {
            int e = eb + j * 1024;
            ok[j] = (e < e1);
            d[j] = ok[j] ? (unsigned int)lde(ei, kE + e, is64) : 0xFFFFFFFFu;
        }
        #pragma unroll
        for (int j = 0; j < 4; j++) {
            int e = eb + j * 1024;
            s[j] = ok[j] ? (unsigned int)lde(ei, e, is64) : 0u;
        }
        #pragma unroll
        for (int j = 0; j < 4; j++) {
            if (d[j] < (unsigned int)kN) {
                unsigned int sv = (s[j] < (unsigned int)kN) ? s[j] : 0u;
                int p = atomicAdd(&cur[d[j] >> 6], 1);
                pairs[p] = (sv << 6) | (d[j] & 63u);
            }
        }
    }
}

// ---------- MEGA bucket kernel: CSR build + layer-1 agg (register acc) + MFMA dense ----------
__global__ void __launch_bounds__(256) GCN_2190433321521_kernel(
        const unsigned int* __restrict__ pairs,
        const int* __restrict__ bbase,
        const uint4* __restrict__ xpack,
        const unsigned short* __restrict__ fwfrag,
        const unsigned short* __restrict__ w2frag,
        int* __restrict__ rp,
        int* __restrict__ col,
        unsigned short* __restrict__ hw,
        const int* __restrict__ flags) {
    __shared__ __align__(16) char smem[25600];
    float*          agg_l  = (float*)smem;                       // [64][29] fp32, 7424 B
    int*            cnt_l  = (int*)(smem + 7424);                // [64] working cursors
    int*            strt_l = (int*)(smem + 7680);                // [64] start cursors
    int*            cntv_l = (int*)(smem + 7936);                // [64] node counts
    unsigned int*   wst    = (unsigned int*)(smem + 8192);       // pair stash [2048], 8 KB
    int*            col_l  = (int*)(smem + 16384);               // col staging [2048], 8 KB
    unsigned short* hbuf   = (unsigned short*)(smem + 8192);     // [4][16][136] (aliases wst+col_l)

    int b = blockIdx.x;
    int base = b * kBN;
    int nn = min(kBN, kN - base);
    int tid = threadIdx.x;
    (void)flags;

    if (tid < kBN) cnt_l[tid] = 0;
    __syncthreads();
    int p0 = bbase[b], p1 = bbase[b + 1];
    int m = p1 - p0;
    bool fits = (m <= kStash);

    // pass 1: load pairs once -> stash + per-node histogram
    for (int ib = p0 + tid; ib < p1; ib += 1024) {
        unsigned int w[4]; int ok[4];
        #pragma unroll
        for (int j = 0; j < 4; j++) {
            int i = ib + j * 256;
            ok[j] = (i < p1);
            w[j] = ok[j] ? pairs[i] : 0u;
        }
        #pragma unroll
        for (int j = 0; j < 4; j++) {
            int i = ib + j * 256;
            if (ok[j]) {
                if (fits) wst[i - p0] = w[j];
                atomicAdd(&cnt_l[w[j] & 63u], 1);
            }
        }
    }
    __syncthreads();
    // wave-0 shfl scan over the 64 node-counts
    if (tid < 64) {
        int v = cnt_l[tid];
        int incl = v;
        #pragma unroll
        for (int o = 1; o < 64; o <<= 1) {
            int y = __shfl_up(incl, o, 64);
            if (tid >= o) incl += y;
        }
        int cursor = p0 + incl - v;
        cnt_l[tid]  = cursor;
        strt_l[tid] = cursor;
        cntv_l[tid] = v;
        if (tid < nn) rp[base + tid] = cursor;
        if (b == kNB - 1 && tid == 0) rp[kN] = p1;
    }
    __syncthreads();

    // pass 2a: col build only (1 LDS atomic per edge)
    for (int i = p0 + tid; i < p1; i += 256) {
        unsigned int w = fits ? wst[i - p0] : pairs[i];
        unsigned int s = w >> 6;
        int dloc = (int)(w & 63u);
        int pos = atomicAdd(&cnt_l[dloc], 1);
        if (fits) col_l[pos - p0] = (int)s;
        else      col[pos] = (int)s;
    }
    __syncthreads();
    if (fits) {
        for (int i = tid; i < m; i += 256) col[p0 + i] = col_l[i];
    }

    // pass 2b: 4 threads per node; register accumulation of 27 slots
    {
        int node = tid >> 2, j = tid & 3;
        float aR[8], aU[8], aP[8];
        #pragma unroll
        for (int i = 0; i < 8; i++) { aR[i] = 0.f; aU[i] = 0.f; aP[i] = 0.f; }
        float cR = 0.f, cU = 0.f, cP = 0.f;
        int start = strt_l[node] - p0;
        int c = cntv_l[node];
        for (int i = start + j; i < start + c; i += 4) {
            int s = fits ? col_l[i] : col[p0 + i];
            uint4 u = xpack[s];
            float2 q0 = bf2_to_f2(u.x), q1 = bf2_to_f2(u.y);
            float2 q2 = bf2_to_f2(u.z), q3 = bf2_to_f2(u.w);
            if (s < kNR) {
                aR[0]+=q0.x; aR[1]+=q0.y; aR[2]+=q1.x; aR[3]+=q1.y;
                aR[4]+=q2.x; aR[5]+=q2.y; aR[6]+=q3.x; aR[7]+=q3.y; cR += 1.f;
            } else if (s < kNR + kNU) {
                aU[0]+=q0.x; aU[1]+=q0.y; aU[2]+=q1.x; aU[3]+=q1.y;
                aU[4]+=q2.x; aU[5]+=q2.y; aU[6]+=q3.x; aU[7]+=q3.y; cU += 1.f;
            } else {
                aP[0]+=q0.x; aP[1]+=q0.y; aP[2]+=q1.x; aP[3]+=q1.y;
                aP[4]+=q2.x; aP[5]+=q2.y; aP[6]+=q3.x; aP[7]+=q3.y; cP += 1.f;
            }
        }
        #pragma unroll
        for (int i = 0; i < 8; i++) {
            float v = aR[i];
            v += __shfl_xor(v, 1, 64);  v += __shfl_xor(v, 2, 64);
            if (j == 0) agg_l[node * 29 + i] = v;
        }
        #pragma unroll
        for (int i = 0; i < 8; i++) {
            float v = aU[i];
            v += __shfl_xor(v, 1, 64);  v += __shfl_xor(v, 2, 64);
            if (j == 0) agg_l[node * 29 + 8 + i] = v;
        }
        #pragma unroll
        for (int i = 0; i < 8; i++) {
            float v = aP[i];
            v += __shfl_xor(v, 1, 64);  v += __shfl_xor(v, 2, 64);
            if (j == 0) agg_l[node * 29 + 16 + i] = v;
        }
        float v = cR;
        v += __shfl_xor(v, 1, 64);  v += __shfl_xor(v, 2, 64);
        if (j == 0) agg_l[node * 29 + 24] = v;
        v = cU;
        v += __shfl_xor(v, 1, 64);  v += __shfl_xor(v, 2, 64);
        if (j == 0) agg_l[node * 29 + 25] = v;
        v = cP;
        v += __shfl_xor(v, 1, 64);  v += __shfl_xor(v, 2, 64);
        if (j == 0) agg_l[node * 29 + 26] = v;
    }
    __syncthreads();   // agg_l complete; wst/col_l dead -> hbuf region live

    // ---- fused dense (MFMA): each wave = one 16-node tile; B-frags from global ----
    int wid = tid >> 6, lane = tid & 63;
    int mm = lane & 15, q = lane >> 4;
    int node = wid * 16 + mm;
    bf16x8 a1;
    #pragma unroll
    for (int j = 0; j < 8; j++) {
        int sl = q * 8 + j;
        a1[j] = (sl < 27) ? (short)f_to_bf(agg_l[node * 29 + sl]) : (short)0;
    }
    const bf16x8* fwf = (const bf16x8*)fwfrag;
    f32x4 c1[8];
    #pragma unroll
    for (int t = 0; t < 8; t++) {
        f32x4 z = {0.f, 0.f, 0.f, 0.f};
        c1[t] = __builtin_amdgcn_mfma_f32_16x16x32_bf16(a1, fwf[t * 64 + lane], z, 0, 0, 0);
    }
    unsigned short* hb = hbuf + wid * 16 * 136;
    #pragma unroll
    for (int t = 0; t < 8; t++) {
        #pragma unroll
        for (int r = 0; r < 4; r++)
            hb[(q * 4 + r) * 136 + 16 * t + mm] = f_to_bf(fmaxf(c1[t][r], 0.f));
    }
    const bf16x8* w2f = (const bf16x8*)w2frag;
    f32x4 c2[3];
    #pragma unroll
    for (int t = 0; t < 3; t++) { c2[t].x = 0.f; c2[t].y = 0.f; c2[t].z = 0.f; c2[t].w = 0.f; }
    #pragma unroll
    for (int s = 0; s < 4; s++) {
        bf16x8 a2 = *(const bf16x8*)&hb[mm * 136 + s * 32 + q * 8];
        #pragma unroll
        for (int t = 0; t < 3; t++)
            c2[t] = __builtin_amdgcn_mfma_f32_16x16x32_bf16(a2, w2f[(s * 3 + t) * 64 + lane],
                                                            c2[t], 0, 0, 0);
    }
    #pragma unroll
    for (int t = 0; t < 3; t++) {
        int cls = 16 * t + mm;
        if (cls < kC) {
            #pragma unroll
            for (int r = 0; r < 4; r++) {
                int n = base + wid * 16 + q * 4 + r;
                if (n < kN) hw[(size_t)n * kC + cls] = f_to_bf(c2[t][r]);
            }
        }
    }
}

// ---------- layer-2 gather: wave-per-node, 6 groups x 10 lanes x dwordx2 ----------
__global__ void __launch_bounds__(256) gcn_gather2(const unsigned int* __restrict__ hw32,
                                                   const int* __restrict__ rp,
                                                   const int* __restrict__ col,
                                                   unsigned int* __restrict__ out,
                                                   const int* __restrict__ flags) {
    int isbf = flags[0];
    int w = (blockIdx.x * 256 + threadIdx.x) >> 6;
    if (w >= kN) return;
    int lane = threadIdx.x & 63;
    int grp = lane / 10;          // 0..5 active, lanes 60-63 idle
    int c2  = lane % 10;          // dword-pair index: classes 4*c2 .. 4*c2+3
    int beg = rp[w], end = rp[w + 1];
    float f0 = 0.f, f1 = 0.f, f2 = 0.f, f3 = 0.f;
    if (grp < 6) {
        const uint2* hp = (const uint2*)hw32;
        int e = beg + grp;
        for (; e + 6 < end; e += 12) {             // 2 edges in flight per group
            int s0 = col[e], s1 = col[e + 6];
            uint2 v0 = hp[s0 * 10 + c2];
            uint2 v1 = hp[s1 * 10 + c2];
            float2 a0 = bf2_to_f2(v0.x), b0 = bf2_to_f2(v0.y);
            float2 a1 = bf2_to_f2(v1.x), b1 = bf2_to_f2(v1.y);
            f0 += a0.x + a1.x;  f1 += a0.y + a1.y;
            f2 += b0.x + b1.x;  f3 += b0.y + b1.y;
        }
        if (e < end) {
            uint2 v = hp[col[e] * 10 + c2];
            float2 a = bf2_to_f2(v.x), bb = bf2_to_f2(v.y);
            f0 += a.x; f1 += a.y; f2 += bb.x; f3 += bb.y;
        }
    }
    f0 += __shfl(f0, lane + 30, 64);
    f1 += __shfl(f1, lane + 30, 64);
    f2 += __shfl(f2, lane + 30, 64);
    f3 += __shfl(f3, lane + 30, 64);
    f0 += __shfl(f0, lane + 10, 64) + __shfl(f0, lane + 20, 64);
    f1 += __shfl(f1, lane + 10, 64) + __shfl(f1, lane + 20, 64);
    f2 += __shfl(f2, lane + 10, 64) + __shfl(f2, lane + 20, 64);
    f3 += __shfl(f3, lane + 10, 64) + __shfl(f3, lane + 20, 64);
    if (lane < 10) {
        if (isbf) {
            out[w * 20 + 2 * lane]     = pack_bf2(f0, f1);
            out[w * 20 + 2 * lane + 1] = pack_bf2(f2, f3);
        } else {
            float* of = (float*)out;
            of[w * 40 + 4 * lane]     = f0;
            of[w * 40 + 4 * lane + 1] = f1;
            of[w * 40 + 4 * lane + 2] = f2;
            of[w * 40 + 4 * lane + 3] = f3;
        }
    }
}

extern "C" void kernel_launch(void* const* d_in, const int* in_sizes, int n_in,
                              void* d_out, int out_size, void* d_ws, size_t ws_size,
                              hipStream_t stream) {
    const void* xr = d_in[0];
    const void* xu = d_in[1];
    const void* xp = d_in[2];
    const int*  ei = (const int*)d_in[3];
    const void* Wr = d_in[4];
    const void* br = d_in[5];
    const void* Wu = d_in[6];
    const void* bu = d_in[7];
    const void* Wp = d_in[8];
    const void* bp = d_in[9];
    const void* W1 = d_in[10];
    const void* W2 = d_in[11];
    (void)in_sizes; (void)n_in; (void)out_size; (void)ws_size;

    char* ws = (char*)d_ws;
    size_t off = 0;
    auto alloc = [&](size_t bytes) -> void* {
        void* p = (void*)(ws + off);
        off = (off + bytes + 255) & ~(size_t)255;
        return p;
    };
    int*            flags  = (int*)           alloc(256);
    int*            cmat   = (int*)           alloc((size_t)kCH * kNBp * 4);  // 1.6 MB
    int*            reloff = (int*)           alloc((size_t)kNB * 256 * 4);   // 1.6 MB
    int*            btot   = (int*)           alloc((size_t)kNB * 4);
    int*            bbase  = (int*)           alloc((size_t)(kNB + 1) * 4);
    int*            rp     = (int*)           alloc((size_t)(kN + 1) * 4);
    unsigned short* fwfrag = (unsigned short*)alloc(8 * 64 * 8 * 2);          // 8 KB
    unsigned short* w2frag = (unsigned short*)alloc(12 * 64 * 8 * 2);         // 12 KB
    uint4*          xpack  = (uint4*)         alloc((size_t)kN * 16);         // 1.6 MB
    unsigned int*   pairs  = (unsigned int*)  alloc((size_t)kE * 4);          // 6.4 MB
    int*            col    = (int*)           alloc((size_t)kE * 4);          // 6.4 MB
    unsigned short* hwb    = (unsigned short*)alloc((size_t)kN * kC * 2);     // 8 MB

    gcn_sniff<<<1, 64, 0, stream>>>((const unsigned int*)W1, ei, flags);
    gcn_setup<<<kSetupB, 512, 0, stream>>>(xr, xu, xp, Wr, br, Wu, bu, Wp, bp, W1, W2,
                                           ei, fwfrag, w2frag, xpack, cmat, flags);
    gcn_scanB<<<kNB, 256, 0, stream>>>(cmat, reloff, btot, bbase, flags + 8);
    gcn_scatter<<<kCH / kSG, 1024, 0, stream>>>(ei, bbase, reloff, pairs, flags);
    GCN_2190433321521_kernel<<<kNB, 256, 0, stream>>>(pairs, bbase, xpack, fwfrag, w2frag,
                                                      rp, col, hwb, flags);
    gcn_gather2<<<(kN * 64 + 255) / 256, 256, 0, stream>>>((const unsigned int*)hwb, rp, col,
                                                           (unsigned int*)d_out, flags);
}

// Round 20
// 203.013 us; speedup vs baseline: 1.1641x; 1.1641x over previous
//
#include <hip/hip_runtime.h>

constexpr int kNR = 40000;
constexpr int kNU = 30000;
constexpr int kNP = 30000;
constexpr int kN  = 100000;          // total nodes
constexpr int kE  = 1600000;         // edges
constexpr int kF  = 128;             // feature/hidden dim
constexpr int kC  = 40;              // classes
constexpr int kBN = 64;              // nodes per bucket
constexpr int kNB = (kN + kBN - 1) / kBN;   // 1563 buckets
constexpr int kNBp = 1600;           // padded bucket-count stride
constexpr int kCH = 256;             // edge chunks (count/scan granularity)
constexpr int kCE = kE / kCH;        // 6250 edges per chunk
constexpr int kSG = 1;               // chunks per scatter block (256 blocks)
constexpr int kStash = 2048;         // LDS pair-stash capacity (avg bucket 1024)
constexpr int kPackB = 196;          // pack blocks (512 thr): 196*512 >= kN
constexpr int kSetupB = kPackB + 2 + kCH;   // 454 blocks total

typedef __attribute__((ext_vector_type(8))) short bf16x8;   // MFMA A/B frag
typedef __attribute__((ext_vector_type(4))) float f32x4;    // MFMA C/D frag

// ---------- bf16 helpers ----------
__device__ __forceinline__ float bf_to_f(unsigned short h) {
    union { unsigned int i; float f; } u; u.i = ((unsigned int)h) << 16; return u.f;
}
__device__ __forceinline__ unsigned short f_to_bf(float f) {
    union { unsigned int i; float f; } u; u.f = f;
    unsigned int r = u.i + 0x7FFFu + ((u.i >> 16) & 1u);   // RNE
    return (unsigned short)(r >> 16);
}
__device__ __forceinline__ float2 bf2_to_f2(unsigned int p) {
    union { unsigned int i; float f; } lo, hi;
    lo.i = (p & 0xFFFFu) << 16;
    hi.i = p & 0xFFFF0000u;
    return make_float2(lo.f, hi.f);
}
__device__ __forceinline__ unsigned int pack_bf2(float a, float b) {
    return (unsigned int)f_to_bf(a) | ((unsigned int)f_to_bf(b) << 16);
}
__device__ __forceinline__ float ldf(const void* p, int i, int isbf) {
    return isbf ? bf_to_f(((const unsigned short*)p)[i]) : ((const float*)p)[i];
}
__device__ __forceinline__ int lde(const int* p, int i, int is64) {
    return is64 ? p[2 * i] : p[i];
}

// ---------- sniff dtypes -> flags[0]=isbf, flags[1]=is64 ----------
__global__ void gcn_sniff(const unsigned int* __restrict__ w1w,
                          const int* __restrict__ eiw, int* __restrict__ flags) {
    if (blockIdx.x != 0 || threadIdx.x != 0) return;
    int plaus = 0;
    for (int k = 0; k < 64; k++) {
        unsigned int ax = w1w[k] & 0x7FFFu;
        plaus += (ax == 0u) || (ax > 0x2000u && ax < 0x4000u);
    }
    flags[0] = (plaus >= 48) ? 1 : 0;
    int nz = 0;
    for (int k = 0; k < 64; k++) nz |= eiw[2 * k + 1];
    flags[1] = (nz == 0) ? 1 : 0;
}

// ---------- MERGED setup+count: blocks 0..195 pack | 196 fuse | 197 w2frag | 198..453 count ----------
// setup and count are independent -> run concurrently in one dispatch (saves ~25us serial).
__global__ void __launch_bounds__(512) gcn_setup(
        const void* __restrict__ xr, const void* __restrict__ xu, const void* __restrict__ xp,
        const void* __restrict__ Wr, const void* __restrict__ br,
        const void* __restrict__ Wu, const void* __restrict__ bu,
        const void* __restrict__ Wp, const void* __restrict__ bp,
        const void* __restrict__ W1, const void* __restrict__ W2,
        const int* __restrict__ ei,
        unsigned short* __restrict__ fwfrag, unsigned short* __restrict__ w2frag,
        uint4* __restrict__ xpack, int* __restrict__ cmat,
        const int* __restrict__ flags) {
    __shared__ __align__(16) char smem[29696];
    int isbf = flags[0];
    int t = threadIdx.x;
    int bx = blockIdx.x;
    if (bx < kPackB) {                       // ---- pack (512 thr) ----
        int n = bx * 512 + t;
        if (n >= kN) return;
        const void* base; int roff, d;
        if (n < kNR)            { base = xr; roff = n * 5;               d = 5; }
        else if (n < kNR + kNU) { base = xu; roff = (n - kNR) * 7;       d = 7; }
        else                    { base = xp; roff = (n - kNR - kNU) * 6; d = 6; }
        float f[8];
        #pragma unroll
        for (int i = 0; i < 8; i++) f[i] = (i < d) ? ldf(base, roff + i, isbf) : 0.f;
        uint4 u;
        u.x = pack_bf2(f[0], f[1]);  u.y = pack_bf2(f[2], f[3]);
        u.z = pack_bf2(f[4], f[5]);  u.w = pack_bf2(f[6], f[7]);
        xpack[n] = u;
    } else if (bx == kPackB) {               // ---- fuse -> fwfrag (split-k, 256 active) ----
        float* sw   = (float*)smem;                          // 21*128 f32 = 10752 B
        float* pacc = (float*)(smem + 10752);                // 10752 B
        unsigned short* flds = (unsigned short*)(smem + 21504);  // 8192 B
        for (int i = t; i < 21 * kF; i += 512) {
            int r = i >> 7, c = i & 127;
            float v;
            if (r < 5)        v = ldf(Wr, r * kF + c, isbf);
            else if (r < 12)  v = ldf(Wu, (r - 5) * kF + c, isbf);
            else if (r < 18)  v = ldf(Wp, (r - 12) * kF + c, isbf);
            else if (r == 18) v = ldf(br, c, isbf);
            else if (r == 19) v = ldf(bu, c, isbf);
            else              v = ldf(bp, c, isbf);
            sw[i] = v;
        }
        __syncthreads();
        {
            bool active = (t < 256);
            int j = t & 127, half = (t >> 7) & 1;
            float acc[21];
            #pragma unroll
            for (int r = 0; r < 21; r++) acc[r] = 0.f;
            if (active) {
                int k0 = half * 64, k1 = k0 + 64;
                for (int k = k0; k < k1; k++) {
                    float w1 = ldf(W1, k * kF + j, isbf);
                    #pragma unroll
                    for (int r = 0; r < 21; r++) acc[r] += sw[r * kF + k] * w1;
                }
            }
            if (active && half == 1) {
                #pragma unroll
                for (int r = 0; r < 21; r++) pacc[r * kF + j] = acc[r];
            }
            __syncthreads();
            if (active && half == 0) {
                #pragma unroll
                for (int r = 0; r < 21; r++) acc[r] += pacc[r * kF + j];
                unsigned short row[32];
                #pragma unroll
                for (int s = 0; s < 32; s++) row[s] = 0;
                #pragma unroll
                for (int i = 0; i < 5; i++) row[0  + i] = f_to_bf(acc[i]);
                #pragma unroll
                for (int i = 0; i < 7; i++) row[8  + i] = f_to_bf(acc[5 + i]);
                #pragma unroll
                for (int i = 0; i < 6; i++) row[16 + i] = f_to_bf(acc[12 + i]);
                row[24] = f_to_bf(acc[18]);  row[25] = f_to_bf(acc[19]);  row[26] = f_to_bf(acc[20]);
                #pragma unroll
                for (int s = 0; s < 32; s++) flds[j * 32 + s] = row[s];
            }
        }
        __syncthreads();
        for (int idx = t; idx < 8 * 64; idx += 512) {
            int t8 = idx >> 6, lane = idx & 63;
            int mm = lane & 15, q = lane >> 4;
            #pragma unroll
            for (int j = 0; j < 8; j++)
                fwfrag[idx * 8 + j] = flds[(16 * t8 + mm) * 32 + q * 8 + j];
        }
    } else if (bx == kPackB + 1) {           // ---- W2 -> w2frag ----
        for (int idx = t; idx < 12 * 64; idx += 512) {
            int st = idx >> 6, lane = idx & 63;
            int s = st / 3, tt = st % 3;
            int mm = lane & 15, q = lane >> 4;
            int cls = 16 * tt + mm;
            #pragma unroll
            for (int j = 0; j < 8; j++) {
                int k = s * 32 + q * 8 + j;
                w2frag[idx * 8 + j] = (cls < kC) ? f_to_bf(ldf(W2, k * kC + cls, isbf))
                                                 : (unsigned short)0;
            }
        }
    } else {                                 // ---- count (chunk = bx - kPackB - 2) ----
        int* cl = (int*)smem;                // 1600 ints = 6400 B
        int is64 = flags[1];
        int blk = bx - kPackB - 2;
        for (int i = t; i < kNBp; i += 512) cl[i] = 0;
        __syncthreads();
        int e0 = blk * kCE, e1 = e0 + kCE;
        for (int eb = e0 + t; eb < e1; eb += 2048) {
            unsigned int d[4]; int ok[4];
            #pragma unroll
            for (int j = 0; j < 4; j++) {
                int e = eb + j * 512;
                ok[j] = (e < e1);
                d[j] = ok[j] ? (unsigned int)lde(ei, kE + e, is64) : 0u;
            }
            #pragma unroll
            for (int j = 0; j < 4; j++)
                if (ok[j] && d[j] < (unsigned int)kN) atomicAdd(&cl[d[j] >> 6], 1);
        }
        __syncthreads();
        for (int i = t; i < kNBp; i += 512) cmat[blk * kNBp + i] = cl[i];
    }
}

// ---------- pass 2a: per-bucket scan over chunks ----------
__global__ void gcn_scanB1(const int* __restrict__ cmat, int* __restrict__ reloff,
                           int* __restrict__ btot) {
    __shared__ int lds[256];
    int b = blockIdx.x, t = threadIdx.x;
    int v = cmat[t * kNBp + b];
    int incl = v; lds[t] = incl; __syncthreads();
    for (int o = 1; o < 256; o <<= 1) {
        int y = (t >= o) ? lds[t - o] : 0;
        __syncthreads();
        incl += y; lds[t] = incl;
        __syncthreads();
    }
    reloff[b * 256 + t] = incl - v;
    if (t == 255) btot[b] = incl;
}

// ---------- pass 2b: scan bucket totals -> bbase ----------
__global__ void gcn_scanB2(const int* __restrict__ btot, int* __restrict__ bbase) {
    __shared__ int lds[512];
    int t = threadIdx.x;
    int v[4]; int s = 0;
    #pragma unroll
    for (int j = 0; j < 4; j++) {
        int i = 4 * t + j;
        v[j] = (i < kNB) ? btot[i] : 0;
        s += v[j];
    }
    int incl = s; lds[t] = incl; __syncthreads();
    for (int o = 1; o < 512; o <<= 1) {
        int y = (t >= o) ? lds[t - o] : 0;
        __syncthreads();
        incl += y; lds[t] = incl;
        __syncthreads();
    }
    int excl = incl - s;
    #pragma unroll
    for (int j = 0; j < 4; j++) {
        int i = 4 * t + j;
        if (i < kNB) { bbase[i] = excl; excl += v[j]; }
    }
    if (t == 511) bbase[kNB] = incl;
}

// ---------- pass 3: scatter pairs; 256 blocks x 1 chunk (full CU coverage) ----------
__global__ void __launch_bounds__(1024) gcn_scatter(const int* __restrict__ ei,
                                                    const int* __restrict__ bbase,
                                                    const int* __restrict__ reloff,
                                                    unsigned int* __restrict__ pairs,
                                                    const int* __restrict__ flags) {
    __shared__ int cur[kNB];
    int is64 = flags[1];
    int blk = blockIdx.x, t = threadIdx.x;
    int c0 = blk * kSG;
    for (int i = t; i < kNB; i += 1024) cur[i] = bbase[i] + reloff[i * 256 + c0];
    __syncthreads();
    int e0 = c0 * kCE, e1 = e0 + kSG * kCE;
    for (int eb = e0 + t; eb < e1; eb += 4096) {
        unsigned int d[4], s[4]; int ok[4];
        #pragma unroll
        for (int j = 0; j < 4; j++) {
            int e = eb + j * 1024;
            ok[j] = (e < e1);
            d[j] = ok[j] ? (unsigned int)lde(ei, kE + e, is64) : 0xFFFFFFFFu;
        }
        #pragma unroll
        for (int j = 0; j < 4; j++) {
            int e = eb + j * 1024;
            s[j] = ok[j] ? (unsigned int)lde(ei, e, is64) : 0u;
        }
        #pragma unroll
        for (int j = 0; j < 4; j++) {
            if (d[j] < (unsigned int)kN) {
                unsigned int sv = (s[j] < (unsigned int)kN) ? s[j] : 0u;
                int p = atomicAdd(&cur[d[j] >> 6], 1);
                pairs[p] = (sv << 6) | (d[j] & 63u);
            }
        }
    }
}

// ---------- MEGA bucket kernel: CSR build + layer-1 agg (register acc) + MFMA dense ----------
__global__ void __launch_bounds__(256) GCN_2190433321521_kernel(
        const unsigned int* __restrict__ pairs,
        const int* __restrict__ bbase,
        const uint4* __restrict__ xpack,
        const unsigned short* __restrict__ fwfrag,
        const unsigned short* __restrict__ w2frag,
        int* __restrict__ rp,
        int* __restrict__ col,
        unsigned short* __restrict__ hw,
        const int* __restrict__ flags) {
    __shared__ __align__(16) char smem[25600];
    float*          agg_l  = (float*)smem;                       // [64][29] fp32, 7424 B
    int*            cnt_l  = (int*)(smem + 7424);                // [64] working cursors
    int*            strt_l = (int*)(smem + 7680);                // [64] start cursors
    int*            cntv_l = (int*)(smem + 7936);                // [64] node counts
    unsigned int*   wst    = (unsigned int*)(smem + 8192);       // pair stash [2048], 8 KB
    int*            col_l  = (int*)(smem + 16384);               // col staging [2048], 8 KB
    unsigned short* hbuf   = (unsigned short*)(smem + 8192);     // [4][16][136] (aliases wst+col_l)

    int b = blockIdx.x;
    int base = b * kBN;
    int nn = min(kBN, kN - base);
    int tid = threadIdx.x;
    (void)flags;

    if (tid < kBN) cnt_l[tid] = 0;
    __syncthreads();
    int p0 = bbase[b], p1 = bbase[b + 1];
    int m = p1 - p0;
    bool fits = (m <= kStash);

    // pass 1: load pairs once -> stash + per-node histogram
    for (int ib = p0 + tid; ib < p1; ib += 1024) {
        unsigned int w[4]; int ok[4];
        #pragma unroll
        for (int j = 0; j < 4; j++) {
            int i = ib + j * 256;
            ok[j] = (i < p1);
            w[j] = ok[j] ? pairs[i] : 0u;
        }
        #pragma unroll
        for (int j = 0; j < 4; j++) {
            int i = ib + j * 256;
            if (ok[j]) {
                if (fits) wst[i - p0] = w[j];
                atomicAdd(&cnt_l[w[j] & 63u], 1);
            }
        }
    }
    __syncthreads();
    // wave-0 shfl scan over the 64 node-counts
    if (tid < 64) {
        int v = cnt_l[tid];
        int incl = v;
        #pragma unroll
        for (int o = 1; o < 64; o <<= 1) {
            int y = __shfl_up(incl, o, 64);
            if (tid >= o) incl += y;
        }
        int cursor = p0 + incl - v;
        cnt_l[tid]  = cursor;
        strt_l[tid] = cursor;
        cntv_l[tid] = v;
        if (tid < nn) rp[base + tid] = cursor;
        if (b == kNB - 1 && tid == 0) rp[kN] = p1;
    }
    __syncthreads();

    // pass 2a: col build only (1 LDS atomic per edge)
    for (int i = p0 + tid; i < p1; i += 256) {
        unsigned int w = fits ? wst[i - p0] : pairs[i];
        unsigned int s = w >> 6;
        int dloc = (int)(w & 63u);
        int pos = atomicAdd(&cnt_l[dloc], 1);
        if (fits) col_l[pos - p0] = (int)s;
        else      col[pos] = (int)s;
    }
    __syncthreads();
    if (fits) {
        for (int i = tid; i < m; i += 256) col[p0 + i] = col_l[i];
    }

    // pass 2b: 4 threads per node; register accumulation of 27 slots
    {
        int node = tid >> 2, j = tid & 3;
        float aR[8], aU[8], aP[8];
        #pragma unroll
        for (int i = 0; i < 8; i++) { aR[i] = 0.f; aU[i] = 0.f; aP[i] = 0.f; }
        float cR = 0.f, cU = 0.f, cP = 0.f;
        int start = strt_l[node] - p0;
        int c = cntv_l[node];
        for (int i = start + j; i < start + c; i += 4) {
            int s = fits ? col_l[i] : col[p0 + i];
            uint4 u = xpack[s];
            float2 q0 = bf2_to_f2(u.x), q1 = bf2_to_f2(u.y);
            float2 q2 = bf2_to_f2(u.z), q3 = bf2_to_f2(u.w);
            if (s < kNR) {
                aR[0]+=q0.x; aR[1]+=q0.y; aR[2]+=q1.x; aR[3]+=q1.y;
                aR[4]+=q2.x; aR[5]+=q2.y; aR[6]+=q3.x; aR[7]+=q3.y; cR += 1.f;
            } else if (s < kNR + kNU) {
                aU[0]+=q0.x; aU[1]+=q0.y; aU[2]+=q1.x; aU[3]+=q1.y;
                aU[4]+=q2.x; aU[5]+=q2.y; aU[6]+=q3.x; aU[7]+=q3.y; cU += 1.f;
            } else {
                aP[0]+=q0.x; aP[1]+=q0.y; aP[2]+=q1.x; aP[3]+=q1.y;
                aP[4]+=q2.x; aP[5]+=q2.y; aP[6]+=q3.x; aP[7]+=q3.y; cP += 1.f;
            }
        }
        #pragma unroll
        for (int i = 0; i < 8; i++) {
            float v = aR[i];
            v += __shfl_xor(v, 1, 64);  v += __shfl_xor(v, 2, 64);
            if (j == 0) agg_l[node * 29 + i] = v;
        }
        #pragma unroll
        for (int i = 0; i < 8; i++) {
            float v = aU[i];
            v += __shfl_xor(v, 1, 64);  v += __shfl_xor(v, 2, 64);
            if (j == 0) agg_l[node * 29 + 8 + i] = v;
        }
        #pragma unroll
        for (int i = 0; i < 8; i++) {
            float v = aP[i];
            v += __shfl_xor(v, 1, 64);  v += __shfl_xor(v, 2, 64);
            if (j == 0) agg_l[node * 29 + 16 + i] = v;
        }
        float v = cR;
        v += __shfl_xor(v, 1, 64);  v += __shfl_xor(v, 2, 64);
        if (j == 0) agg_l[node * 29 + 24] = v;
        v = cU;
        v += __shfl_xor(v, 1, 64);  v += __shfl_xor(v, 2, 64);
        if (j == 0) agg_l[node * 29 + 25] = v;
        v = cP;
        v += __shfl_xor(v, 1, 64);  v += __shfl_xor(v, 2, 64);
        if (j == 0) agg_l[node * 29 + 26] = v;
    }
    __syncthreads();   // agg_l complete; wst/col_l dead -> hbuf region live

    // ---- fused dense (MFMA): each wave = one 16-node tile; B-frags from global ----
    int wid = tid >> 6, lane = tid & 63;
    int mm = lane & 15, q = lane >> 4;
    int node = wid * 16 + mm;
    bf16x8 a1;
    #pragma unroll
    for (int j = 0; j < 8; j++) {
        int sl = q * 8 + j;
        a1[j] = (sl < 27) ? (short)f_to_bf(agg_l[node * 29 + sl]) : (short)0;
    }
    const bf16x8* fwf = (const bf16x8*)fwfrag;
    f32x4 c1[8];
    #pragma unroll
    for (int t = 0; t < 8; t++) {
        f32x4 z = {0.f, 0.f, 0.f, 0.f};
        c1[t] = __builtin_amdgcn_mfma_f32_16x16x32_bf16(a1, fwf[t * 64 + lane], z, 0, 0, 0);
    }
    unsigned short* hb = hbuf + wid * 16 * 136;
    #pragma unroll
    for (int t = 0; t < 8; t++) {
        #pragma unroll
        for (int r = 0; r < 4; r++)
            hb[(q * 4 + r) * 136 + 16 * t + mm] = f_to_bf(fmaxf(c1[t][r], 0.f));
    }
    const bf16x8* w2f = (const bf16x8*)w2frag;
    f32x4 c2[3];
    #pragma unroll
    for (int t = 0; t < 3; t++) { c2[t].x = 0.f; c2[t].y = 0.f; c2[t].z = 0.f; c2[t].w = 0.f; }
    #pragma unroll
    for (int s = 0; s < 4; s++) {
        bf16x8 a2 = *(const bf16x8*)&hb[mm * 136 + s * 32 + q * 8];
        #pragma unroll
        for (int t = 0; t < 3; t++)
            c2[t] = __builtin_amdgcn_mfma_f32_16x16x32_bf16(a2, w2f[(s * 3 + t) * 64 + lane],
                                                            c2[t], 0, 0, 0);
    }
    #pragma unroll
    for (int t = 0; t < 3; t++) {
        int cls = 16 * t + mm;
        if (cls < kC) {
            #pragma unroll
            for (int r = 0; r < 4; r++) {
                int n = base + wid * 16 + q * 4 + r;
                if (n < kN) hw[(size_t)n * kC + cls] = f_to_bf(c2[t][r]);
            }
        }
    }
}

// ---------- layer-2 gather: wave-per-node, 6 groups x 10 lanes x dwordx2 ----------
__global__ void __launch_bounds__(256) gcn_gather2(const unsigned int* __restrict__ hw32,
                                                   const int* __restrict__ rp,
                                                   const int* __restrict__ col,
                                                   unsigned int* __restrict__ out,
                                                   const int* __restrict__ flags) {
    int isbf = flags[0];
    int w = (blockIdx.x * 256 + threadIdx.x) >> 6;
    if (w >= kN) return;
    int lane = threadIdx.x & 63;
    int grp = lane / 10;          // 0..5 active, lanes 60-63 idle
    int c2  = lane % 10;          // dword-pair index: classes 4*c2 .. 4*c2+3
    int beg = rp[w], end = rp[w + 1];
    float f0 = 0.f, f1 = 0.f, f2 = 0.f, f3 = 0.f;
    if (grp < 6) {
        const uint2* hp = (const uint2*)hw32;
        int e = beg + grp;
        for (; e + 6 < end; e += 12) {             // 2 edges in flight per group
            int s0 = col[e], s1 = col[e + 6];
            uint2 v0 = hp[s0 * 10 + c2];
            uint2 v1 = hp[s1 * 10 + c2];
            float2 a0 = bf2_to_f2(v0.x), b0 = bf2_to_f2(v0.y);
            float2 a1 = bf2_to_f2(v1.x), b1 = bf2_to_f2(v1.y);
            f0 += a0.x + a1.x;  f1 += a0.y + a1.y;
            f2 += b0.x + b1.x;  f3 += b0.y + b1.y;
        }
        if (e < end) {
            uint2 v = hp[col[e] * 10 + c2];
            float2 a = bf2_to_f2(v.x), bb = bf2_to_f2(v.y);
            f0 += a.x; f1 += a.y; f2 += bb.x; f3 += bb.y;
        }
    }
    f0 += __shfl(f0, lane + 30, 64);
    f1 += __shfl(f1, lane + 30, 64);
    f2 += __shfl(f2, lane + 30, 64);
    f3 += __shfl(f3, lane + 30, 64);
    f0 += __shfl(f0, lane + 10, 64) + __shfl(f0, lane + 20, 64);
    f1 += __shfl(f1, lane + 10, 64) + __shfl(f1, lane + 20, 64);
    f2 += __shfl(f2, lane + 10, 64) + __shfl(f2, lane + 20, 64);
    f3 += __shfl(f3, lane + 10, 64) + __shfl(f3, lane + 20, 64);
    if (lane < 10) {
        if (isbf) {
            out[w * 20 + 2 * lane]     = pack_bf2(f0, f1);
            out[w * 20 + 2 * lane + 1] = pack_bf2(f2, f3);
        } else {
            float* of = (float*)out;
            of[w * 40 + 4 * lane]     = f0;
            of[w * 40 + 4 * lane + 1] = f1;
            of[w * 40 + 4 * lane + 2] = f2;
            of[w * 40 + 4 * lane + 3] = f3;
        }
    }
}

extern "C" void kernel_launch(void* const* d_in, const int* in_sizes, int n_in,
                              void* d_out, int out_size, void* d_ws, size_t ws_size,
                              hipStream_t stream) {
    const void* xr = d_in[0];
    const void* xu = d_in[1];
    const void* xp = d_in[2];
    const int*  ei = (const int*)d_in[3];
    const void* Wr = d_in[4];
    const void* br = d_in[5];
    const void* Wu = d_in[6];
    const void* bu = d_in[7];
    const void* Wp = d_in[8];
    const void* bp = d_in[9];
    const void* W1 = d_in[10];
    const void* W2 = d_in[11];
    (void)in_sizes; (void)n_in; (void)out_size; (void)ws_size;

    char* ws = (char*)d_ws;
    size_t off = 0;
    auto alloc = [&](size_t bytes) -> void* {
        void* p = (void*)(ws + off);
        off = (off + bytes + 255) & ~(size_t)255;
        return p;
    };
    int*            flags  = (int*)           alloc(256);
    int*            cmat   = (int*)           alloc((size_t)kCH * kNBp * 4);  // 1.6 MB
    int*            reloff = (int*)           alloc((size_t)kNB * 256 * 4);   // 1.6 MB
    int*            btot   = (int*)           alloc((size_t)kNB * 4);
    int*            bbase  = (int*)           alloc((size_t)(kNB + 1) * 4);
    int*            rp     = (int*)           alloc((size_t)(kN + 1) * 4);
    unsigned short* fwfrag = (unsigned short*)alloc(8 * 64 * 8 * 2);          // 8 KB
    unsigned short* w2frag = (unsigned short*)alloc(12 * 64 * 8 * 2);         // 12 KB
    uint4*          xpack  = (uint4*)         alloc((size_t)kN * 16);         // 1.6 MB
    unsigned int*   pairs  = (unsigned int*)  alloc((size_t)kE * 4);          // 6.4 MB
    int*            col    = (int*)           alloc((size_t)kE * 4);          // 6.4 MB
    unsigned short* hwb    = (unsigned short*)alloc((size_t)kN * kC * 2);     // 8 MB

    gcn_sniff<<<1, 64, 0, stream>>>((const unsigned int*)W1, ei, flags);
    gcn_setup<<<kSetupB, 512, 0, stream>>>(xr, xu, xp, Wr, br, Wu, bu, Wp, bp, W1, W2,
                                           ei, fwfrag, w2frag, xpack, cmat, flags);
    gcn_scanB1<<<kNB, 256, 0, stream>>>(cmat, reloff, btot);
    gcn_scanB2<<<1, 512, 0, stream>>>(btot, bbase);
    gcn_scatter<<<kCH / kSG, 1024, 0, stream>>>(ei, bbase, reloff, pairs, flags);
    GCN_2190433321521_kernel<<<kNB, 256, 0, stream>>>(pairs, bbase, xpack, fwfrag, w2frag,
                                                      rp, col, hwb, flags);
    gcn_gather2<<<(kN * 64 + 255) / 256, 256, 0, stream>>>((const unsigned int*)hwb, rp, col,
                                                           (unsigned int*)d_out, flags);
}